// Round 13
// baseline (84.945 us; speedup 1.0000x reference)
//
#include <hip/hip_runtime.h>
#include <math.h>

#define BB 8
#define SS 2048
#define DD 1024
#define MM 4096
#define dd 256
#define NCH 64          // S-chunks for x column-sum
#define CS (SS/NCH)     // 32 rows per chunk

typedef float f4 __attribute__((ext_vector_type(4)));

// ---- ws layout (floats) ----
#define OFF_PART  0                        // [b*64+chunk][1024] = 524288
#define OFF_Q     524288                   // 2048
#define OFF_WV    526336                   // 2048
#define OFF_GATE  528384                   // 8
#define OFF_COMBO 528392                   // 8
#define OFF_SUMP  528400                   // 2048: [which*1024 + b*128 + mc]
#define OFF_SC    530448                   // 32768: exp write-scores [b][m]
#define OFF_PRET  563216                   // 262144: [(b*128+mc)*256 + j]
#define OFF_ROUT  825360                   // 8192

// K1: x partial column sums. grid = B*NCH = 512, block 256, f4/thread.
__global__ void k1(const float* __restrict__ x, float* __restrict__ ws) {
    int blk = blockIdx.x;
    int chunk = blk & 63;
    int b = blk >> 6;
    int t = threadIdx.x;
    const f4* x4 = (const f4*)(x + ((size_t)b*SS + (size_t)chunk*CS)*DD);
    f4 a = (f4)(0.f);
    #pragma unroll
    for (int s = 0; s < CS; ++s) a += x4[s*256 + t];
    ((f4*)(ws + OFF_PART))[(size_t)blk*256 + t] = a;
}

// K23: fused projections + gate. grid = 72 blocks, block 512. (proven)
__global__ void k23(const float* __restrict__ Wq, const float* __restrict__ bq,
                    const float* __restrict__ Wv, const float* __restrict__ bv,
                    const float* __restrict__ Wg, const float* __restrict__ bg,
                    float* __restrict__ ws) {
    __shared__ f4 xsA[256];
    __shared__ f4 xsB[256];
    __shared__ float red[512];
    int blk = blockIdx.x;
    int t = threadIdx.x;
    const f4* p4 = (const f4*)(ws + OFF_PART);
    if (blk < 64) {
        int cs = blk & 3;
        int wb = blk >> 2;
        int b = wb & 7;
        int which = wb >> 3;
        int col4 = t & 255;
        int half = t >> 8;
        f4 a = (f4)(0.f);
        #pragma unroll 8
        for (int c = 0; c < 32; ++c)
            a += p4[(size_t)(b*NCH + half*32 + c)*256 + col4];
        if (half == 0) xsA[col4] = a; else xsB[col4] = a;
        __syncthreads();
        if (t < 256) xsA[t] = (xsA[t] + xsB[t]) * (1.f/SS);
        __syncthreads();
        const float* xs = (const float*)xsA;
        const float* W = which ? Wv : Wq;
        int kg = t >> 6;
        int c0 = cs*64 + (t & 63);
        float acc = 0.f;
        #pragma unroll 8
        for (int kk = 0; kk < 128; ++kk) {
            int k = kg*128 + kk;
            acc += xs[k] * W[(size_t)k*dd + c0];
        }
        red[t] = acc;
        __syncthreads();
        if (t < 64) {
            int c = cs*64 + t;
            float o = red[t] + red[t+64] + red[t+128] + red[t+192]
                    + red[t+256] + red[t+320] + red[t+384] + red[t+448];
            o += which ? bv[c] : bq[c];
            ws[(which ? OFF_WV : OFF_Q) + b*dd + c] = o;
        }
    } else {
        int b = blk - 64;
        const float* base = ws + OFF_PART + (size_t)(b*NCH)*DD;
        float wg0 = Wg[t], wg1 = Wg[t + 512];
        float acc = 0.f;
        #pragma unroll 8
        for (int c = 0; c < NCH; ++c) {
            const float* p = base + (size_t)c*DD;
            acc += p[t]*wg0 + p[t+512]*wg1;
        }
        red[t] = acc; __syncthreads();
        for (int s2 = 256; s2 > 0; s2 >>= 1) {
            if (t < s2) red[t] += red[t + s2];
            __syncthreads();
        }
        if (t == 0)
            ws[OFF_GATE + b] = 1.f / (1.f + __expf(-(red[0]*(1.f/SS) + bg[0])));
    }
}

// K45: tile-shared read scores + write scores.
// blocks 0..127: read-side tile mc — all 8 batches from ONE tile of memory[0].
// blocks 128..1151: write-side, b = (blk-128)>>7, mc = (blk-128)&127.
__global__ __launch_bounds__(256, 8)
void k45(const float* __restrict__ memory, float* __restrict__ ws) {
    __shared__ float esc[BB][32];
    __shared__ f4 qs4[BB][64];
    int blk = blockIdx.x;
    int t = threadIdx.x;
    int wave = t >> 6, lane = t & 63;
    if (blk < 128) {
        int mc = blk;
        const float* tile = memory + (size_t)mc*32*dd;
        for (int e = t; e < BB*64; e += 256) {
            int b = e >> 6, j = e & 63;
            qs4[b][j] = ((const f4*)(ws + OFF_Q + b*dd))[j];
        }
        __syncthreads();
        #pragma unroll
        for (int i = 0; i < 8; ++i) {
            int r = i*4 + wave;
            f4 av = ((const f4*)(tile + (size_t)r*dd))[lane];
            #pragma unroll
            for (int b = 0; b < BB; ++b) {
                f4 pr = av * qs4[b][lane];
                float p = pr.x + pr.y + pr.z + pr.w;
                #pragma unroll
                for (int off = 32; off > 0; off >>= 1) p += __shfl_xor(p, off);
                if (lane == 0) esc[b][r] = __expf(p);
            }
        }
        __syncthreads();
        // row-sum partials: thread group of 32 per b (same 16..1 shfl tree as before)
        {
            int b = t >> 5, r = t & 31;
            float v = esc[b][r];
            #pragma unroll
            for (int off = 16; off > 0; off >>= 1) v += __shfl_xor(v, off);
            if (r == 0) ws[OFF_SUMP + b*128 + mc] = v;
        }
        // retrieval partials for all 8 b from the L2-hot tile
        float acc[BB];
        #pragma unroll
        for (int b = 0; b < BB; ++b) acc[b] = 0.f;
        #pragma unroll 4
        for (int i = 0; i < 32; ++i) {
            float val = tile[(size_t)i*dd + t];
            #pragma unroll
            for (int b = 0; b < BB; ++b) acc[b] += esc[b][i] * val;
        }
        #pragma unroll
        for (int b = 0; b < BB; ++b)
            ws[OFF_PRET + (size_t)(b*128 + mc)*dd + t] = acc[b];
    } else {
        int idx = blk - 128;
        int b = idx >> 7;
        int mc = idx & 127;
        const float* tile = memory + (size_t)b*MM*dd + (size_t)mc*32*dd;
        const f4 qv = ((const f4*)(ws + OFF_Q + b*dd))[lane];
        #pragma unroll
        for (int i = 0; i < 8; ++i) {
            int r = i*4 + wave;
            f4 av = ((const f4*)(tile + (size_t)r*dd))[lane];
            f4 pr = av * qv;
            float p = pr.x + pr.y + pr.z + pr.w;
            #pragma unroll
            for (int off = 32; off > 0; off >>= 1) p += __shfl_xor(p, off);
            if (lane == 0) esc[0][r] = __expf(p);
        }
        __syncthreads();
        if (t < 32) {
            float v = esc[0][t];
            #pragma unroll
            for (int off = 16; off > 0; off >>= 1) v += __shfl_xor(v, off);
            if (t == 0) ws[OFF_SUMP + 1024 + b*128 + mc] = v;
        }
        if (t < 32) ws[OFF_SC + (size_t)b*MM + mc*32 + t] = esc[0][t];
    }
}

// K7: SUMP reduce + PRET reduce + normalize + Wo matvec + combo. grid = 128.
__global__ void k7(const float* __restrict__ Wo, const float* __restrict__ bo,
                   float* __restrict__ ws) {
    __shared__ float ret[dd];
    __shared__ float red[256];
    __shared__ float ssum;
    int blk = blockIdx.x;
    int cb = blk & 15;
    int b = blk >> 4;
    int t = threadIdx.x;
    if (t < 64) {
        float v = ws[OFF_SUMP + b*128 + t] + ws[OFF_SUMP + b*128 + 64 + t];
        #pragma unroll
        for (int off = 32; off > 0; off >>= 1) v += __shfl_xor(v, off);
        if (t == 0) ssum = v;
    } else if (t < 128 && cb == 0) {
        int u = t - 64;
        float v = ws[OFF_SUMP + 1024 + b*128 + u] + ws[OFF_SUMP + 1024 + b*128 + 64 + u];
        #pragma unroll
        for (int off = 32; off > 0; off >>= 1) v += __shfl_xor(v, off);
        if (t == 64) ws[OFF_COMBO + b] = 0.05f * ws[OFF_GATE + b] / v;
    }
    float acc0 = 0.f;
    #pragma unroll 8
    for (int mc = 0; mc < 128; ++mc)
        acc0 += ws[OFF_PRET + (size_t)(b*128 + mc)*dd + t];
    __syncthreads();
    ret[t] = acc0 / ssum;
    __syncthreads();
    int c = t & 63, jr = t >> 6;
    float acc = 0.f;
    #pragma unroll 8
    for (int jj = 0; jj < 64; ++jj) {
        int j = jr*64 + jj;
        acc += ret[j] * Wo[(size_t)j*DD + cb*64 + c];
    }
    red[t] = acc; __syncthreads();
    if (t < 64) {
        ws[OFF_ROUT + (size_t)b*DD + cb*64 + t] =
            red[t] + red[t+64] + red[t+128] + red[t+192] + bo[cb*64 + t];
    }
}

// K8: fused elementwise outputs. f4 grid-stride, grid 4096, nt stores. (R11 proven)
__global__ void k8(const float* __restrict__ x, const float* __restrict__ memory,
                   const float* __restrict__ ws, float* __restrict__ out) {
    const int NA = BB*SS*DD/4;       // 4194304
    const int NT = NA + BB*MM*dd/4;  // 6291456
    const f4* x4 = (const f4*)x;
    const f4* m4 = (const f4*)memory;
    const f4* r4 = (const f4*)(ws + OFF_ROUT);
    const f4* w4 = (const f4*)(ws + OFF_WV);
    f4* o4 = (f4*)out;
    int stride = gridDim.x * blockDim.x;
    for (int i = blockIdx.x*blockDim.x + threadIdx.x; i < NT; i += stride) {
        if (i < NA) {
            int b = i >> 19;
            int c = i & 255;
            f4 o = x4[i] + r4[(b << 8) + c];
            __builtin_nontemporal_store(o, &o4[i]);
        } else {
            int j = i - NA;
            int b = j >> 18;
            int m = (j >> 6) & (MM-1);
            int d4 = j & 63;
            float coeff = ws[OFF_COMBO + b] * ws[OFF_SC + (size_t)b*MM + m];
            f4 o = 0.95f*m4[j] + coeff*w4[(b << 6) + d4];
            __builtin_nontemporal_store(o, &o4[i]);
        }
    }
}

extern "C" void kernel_launch(void* const* d_in, const int* in_sizes, int n_in,
                              void* d_out, int out_size, void* d_ws, size_t ws_size,
                              hipStream_t stream) {
    const float* x      = (const float*)d_in[0];
    const float* memory = (const float*)d_in[1];
    const float* Wq     = (const float*)d_in[2];
    const float* bq     = (const float*)d_in[3];
    const float* Wv     = (const float*)d_in[4];
    const float* bv     = (const float*)d_in[5];
    const float* Wo     = (const float*)d_in[6];
    const float* bo     = (const float*)d_in[7];
    const float* Wg     = (const float*)d_in[8];
    const float* bg     = (const float*)d_in[9];
    float* out = (float*)d_out;
    float* ws  = (float*)d_ws;

    k1<<<BB*NCH, 256, 0, stream>>>(x, ws);
    k23<<<72, 512, 0, stream>>>(Wq, bq, Wv, bv, Wg, bg, ws);
    k45<<<1152, 256, 0, stream>>>(memory, ws);
    k7<<<BB*16, 256, 0, stream>>>(Wo, bo, ws);
    k8<<<4096, 256, 0, stream>>>(x, memory, ws, out);
}

// Round 14
// 73.741 us; speedup vs baseline: 1.1519x; 1.1519x over previous
//
#include <hip/hip_runtime.h>
#include <math.h>

#define BB 8
#define SS 2048
#define DD 1024
#define MM 4096
#define dd 256
#define NCH 64          // S-chunks for x column-sum
#define CS (SS/NCH)     // 32 rows per chunk

// ---- ws layout (floats) ----
#define OFF_PART  0                        // [b*64+chunk][1024] = 524288
#define OFF_Q     524288                   // 2048
#define OFF_WV    526336                   // 2048
#define OFF_GATE  528384                   // 8
#define OFF_COMBO 528392                   // 8
#define OFF_SUMP  528400                   // [which*512 + b*64 + mc] = 1024
#define OFF_SC    529424                   // write-side exp scores [b][m] = 32768
#define OFF_PRET  562192                   // [(b*64+mc)*256+j] = 131072
#define OFF_ROUT  693264                   // 8192

// K1: x partial column sums. grid = B*NCH = 512, block 256, float4/thread.
__global__ void k1(const float* __restrict__ x, float* __restrict__ ws) {
    int blk = blockIdx.x;
    int chunk = blk & 63;
    int b = blk >> 6;
    int t = threadIdx.x;
    const float4* x4 = (const float4*)(x + ((size_t)b*SS + (size_t)chunk*CS)*DD);
    float4 a = make_float4(0.f,0.f,0.f,0.f);
    #pragma unroll 8
    for (int s = 0; s < CS; ++s) {
        float4 v = x4[s*(DD/4) + t];
        a.x += v.x; a.y += v.y; a.z += v.z; a.w += v.w;
    }
    ((float4*)(ws + OFF_PART))[(size_t)blk*256 + t] = a;
}

// K23: fused projections + gate. grid = 72 blocks, block 512.
__global__ void k23(const float* __restrict__ Wq, const float* __restrict__ bq,
                    const float* __restrict__ Wv, const float* __restrict__ bv,
                    const float* __restrict__ Wg, const float* __restrict__ bg,
                    float* __restrict__ ws) {
    __shared__ float4 xsA[256];
    __shared__ float4 xsB[256];
    __shared__ float red[512];
    int blk = blockIdx.x;
    int t = threadIdx.x;
    const float4* p4 = (const float4*)(ws + OFF_PART);
    if (blk < 64) {
        int cs = blk & 3;
        int wb = blk >> 2;
        int b = wb & 7;
        int which = wb >> 3;
        int col4 = t & 255;
        int half = t >> 8;
        float4 a = make_float4(0.f,0.f,0.f,0.f);
        #pragma unroll 8
        for (int c = 0; c < 32; ++c) {
            float4 v = p4[(size_t)(b*NCH + half*32 + c)*256 + col4];
            a.x += v.x; a.y += v.y; a.z += v.z; a.w += v.w;
        }
        if (half == 0) xsA[col4] = a; else xsB[col4] = a;
        __syncthreads();
        if (t < 256) {
            float4 u = xsA[t], v = xsB[t];
            xsA[t] = make_float4((u.x+v.x)*(1.f/SS), (u.y+v.y)*(1.f/SS),
                                 (u.z+v.z)*(1.f/SS), (u.w+v.w)*(1.f/SS));
        }
        __syncthreads();
        const float* xs = (const float*)xsA;
        const float* W = which ? Wv : Wq;
        int kg = t >> 6;
        int c0 = cs*64 + (t & 63);
        float acc = 0.f;
        #pragma unroll 8
        for (int kk = 0; kk < 128; ++kk) {
            int k = kg*128 + kk;
            acc += xs[k] * W[(size_t)k*dd + c0];
        }
        red[t] = acc;
        __syncthreads();
        if (t < 64) {
            int c = cs*64 + t;
            float o = red[t] + red[t+64] + red[t+128] + red[t+192]
                    + red[t+256] + red[t+320] + red[t+384] + red[t+448];
            o += which ? bv[c] : bq[c];
            ws[(which ? OFF_WV : OFF_Q) + b*dd + c] = o;
        }
    } else {
        int b = blk - 64;
        const float* base = ws + OFF_PART + (size_t)(b*NCH)*DD;
        float wg0 = Wg[t], wg1 = Wg[t + 512];
        float acc = 0.f;
        #pragma unroll 8
        for (int c = 0; c < NCH; ++c) {
            const float* p = base + (size_t)c*DD;
            acc += p[t]*wg0 + p[t+512]*wg1;
        }
        red[t] = acc; __syncthreads();
        for (int s2 = 256; s2 > 0; s2 >>= 1) {
            if (t < s2) red[t] += red[t + s2];
            __syncthreads();
        }
        if (t == 0)
            ws[OFF_GATE + b] = 1.f / (1.f + __expf(-(red[0]*(1.f/SS) + bg[0])));
    }
}

// K45: fused scores+exp+rowsum-partial+retrieval-partial.
// grid = 1024: which = blk>>9, b = (blk>>6)&7, mc = blk&63 (64 m-rows per block).
__global__ void k45(const float* __restrict__ memory, float* __restrict__ ws) {
    __shared__ float esc[64];
    int idx = blockIdx.x;
    int which = idx >> 9;
    int b = (idx >> 6) & 7;
    int mc = idx & 63;
    int t = threadIdx.x;
    int wave = t >> 6, lane = t & 63;
    const float* tile = ((which == 0) ? memory : memory + (size_t)b*MM*dd)
                        + (size_t)mc*64*dd;
    const float4 qv = ((const float4*)(ws + OFF_Q + b*dd))[lane];
    #pragma unroll 4
    for (int i = 0; i < 16; ++i) {
        int r = i*4 + wave;
        float4 av = ((const float4*)(tile + (size_t)r*dd))[lane];
        float p = av.x*qv.x + av.y*qv.y + av.z*qv.z + av.w*qv.w;
        #pragma unroll
        for (int off = 32; off > 0; off >>= 1) p += __shfl_xor(p, off);
        if (lane == 0) esc[r] = __expf(p);
    }
    __syncthreads();
    if (t < 64) {
        float v = esc[t];
        #pragma unroll
        for (int off = 32; off > 0; off >>= 1) v += __shfl_xor(v, off);
        if (t == 0) ws[OFF_SUMP + which*512 + b*64 + mc] = v;
    }
    if (which == 0) {
        float acc = 0.f;
        #pragma unroll 8
        for (int i = 0; i < 64; ++i) acc += esc[i] * tile[(size_t)i*dd + t];
        ws[OFF_PRET + (size_t)(b*64 + mc)*dd + t] = acc;
    } else {
        if (t < 64) ws[OFF_SC + (size_t)b*MM + mc*64 + t] = esc[t];
    }
}

// K7: SUMP reduce + PRET reduce + normalize + Wo matvec + combo. grid = 128, block 256.
__global__ void k7(const float* __restrict__ Wo, const float* __restrict__ bo,
                   float* __restrict__ ws) {
    __shared__ float ret[dd];
    __shared__ float red[256];
    __shared__ float ssum;
    int blk = blockIdx.x;
    int cb = blk & 15;
    int b = blk >> 4;
    int t = threadIdx.x;
    if (t < 64) {
        float v = ws[OFF_SUMP + b*64 + t];
        #pragma unroll
        for (int off = 32; off > 0; off >>= 1) v += __shfl_xor(v, off);
        if (t == 0) ssum = v;
    } else if (t < 128 && cb == 0) {
        float v = ws[OFF_SUMP + 512 + b*64 + (t - 64)];
        #pragma unroll
        for (int off = 32; off > 0; off >>= 1) v += __shfl_xor(v, off);
        if (t == 64) ws[OFF_COMBO + b] = 0.05f * ws[OFF_GATE + b] / v;
    }
    float acc0 = 0.f;
    #pragma unroll 8
    for (int mc = 0; mc < 64; ++mc)
        acc0 += ws[OFF_PRET + (size_t)(b*64 + mc)*dd + t];
    __syncthreads();
    ret[t] = acc0 / ssum;
    __syncthreads();
    int c = t & 63, jr = t >> 6;
    float acc = 0.f;
    #pragma unroll 8
    for (int jj = 0; jj < 64; ++jj) {
        int j = jr*64 + jj;
        acc += ret[j] * Wo[(size_t)j*DD + cb*64 + c];
    }
    red[t] = acc; __syncthreads();
    if (t < 64) {
        ws[OFF_ROUT + (size_t)b*DD + cb*64 + t] =
            red[t] + red[t+64] + red[t+128] + red[t+192] + bo[cb*64 + t];
    }
}

// K8: fused elementwise outputs. float4 grid-stride, grid 4096.
__global__ void k8(const float* __restrict__ x, const float* __restrict__ memory,
                   const float* __restrict__ ws, float* __restrict__ out) {
    const int NA = BB*SS*DD/4;       // 4194304
    const int NT = NA + BB*MM*dd/4;  // 6291456
    const float4* x4 = (const float4*)x;
    const float4* m4 = (const float4*)memory;
    const float4* r4 = (const float4*)(ws + OFF_ROUT);
    const float4* w4 = (const float4*)(ws + OFF_WV);
    float4* o4 = (float4*)out;
    int stride = gridDim.x * blockDim.x;
    for (int i = blockIdx.x*blockDim.x + threadIdx.x; i < NT; i += stride) {
        if (i < NA) {
            int b = i >> 19;
            int c = i & 255;
            float4 xv = x4[i];
            float4 rv = r4[(b << 8) + c];
            o4[i] = make_float4(xv.x+rv.x, xv.y+rv.y, xv.z+rv.z, xv.w+rv.w);
        } else {
            int j = i - NA;
            int b = j >> 18;
            int m = (j >> 6) & (MM-1);
            int d4 = j & 63;
            float coeff = ws[OFF_COMBO + b] * ws[OFF_SC + (size_t)b*MM + m];
            float4 wv = w4[(b << 6) + d4];
            float4 mv = m4[j];
            o4[i] = make_float4(0.95f*mv.x + coeff*wv.x,
                                0.95f*mv.y + coeff*wv.y,
                                0.95f*mv.z + coeff*wv.z,
                                0.95f*mv.w + coeff*wv.w);
        }
    }
}

extern "C" void kernel_launch(void* const* d_in, const int* in_sizes, int n_in,
                              void* d_out, int out_size, void* d_ws, size_t ws_size,
                              hipStream_t stream) {
    const float* x      = (const float*)d_in[0];
    const float* memory = (const float*)d_in[1];
    const float* Wq     = (const float*)d_in[2];
    const float* bq     = (const float*)d_in[3];
    const float* Wv     = (const float*)d_in[4];
    const float* bv     = (const float*)d_in[5];
    const float* Wo     = (const float*)d_in[6];
    const float* bo     = (const float*)d_in[7];
    const float* Wg     = (const float*)d_in[8];
    const float* bg     = (const float*)d_in[9];
    float* out = (float*)d_out;
    float* ws  = (float*)d_ws;

    k1<<<BB*NCH, 256, 0, stream>>>(x, ws);
    k23<<<72, 512, 0, stream>>>(Wq, bq, Wv, bv, Wg, bg, ws);
    k45<<<1024, 256, 0, stream>>>(memory, ws);
    k7<<<BB*16, 256, 0, stream>>>(Wo, bo, ws);
    k8<<<4096, 256, 0, stream>>>(x, memory, ws, out);
}